// Round 15
// baseline (239.982 us; speedup 1.0000x reference)
//
#include <hip/hip_runtime.h>
#include <hip/hip_bf16.h>

#define FEAT 64
#define CHUNK 8192   // edges per P1/P3 block
#define MAX_NB 1024  // max buckets (N <= 262144)

typedef __attribute__((ext_vector_type(8))) short bf16x8;
typedef __attribute__((ext_vector_type(4))) float f32x4;
typedef __attribute__((ext_vector_type(2))) float f32x2;

// ---------- bf16 helpers ----------
__device__ __forceinline__ float bflo2f(unsigned int u) {
    union { unsigned int u; float f; } v; v.u = u << 16; return v.f;
}
__device__ __forceinline__ float bfhi2f(unsigned int u) {
    union { unsigned int u; float f; } v; v.u = u & 0xffff0000u; return v.f;
}
__device__ __forceinline__ unsigned short f2bf(float f) {
    union { float f; unsigned int u; } v; v.f = f;
    unsigned int u = v.u;
    u += 0x7fffu + ((u >> 16) & 1u);   // round-to-nearest-even
    return (unsigned short)(u >> 16);
}
__device__ __forceinline__ f32x2 bfpair(unsigned int u) {
    f32x2 r; r.x = bflo2f(u & 0xffffu); r.y = bfhi2f(u); return r;
}

// ---------- 0. prep: per-block dtype detect + weight conversion + x conversion ----------
__global__ __launch_bounds__(256) void prep_kernel(
    const unsigned short* __restrict__ xh, const int* __restrict__ ei32,
    const void* __restrict__ w1a, const void* __restrict__ w1r,
    const void* __restrict__ b1,  const void* __restrict__ w2a,
    const void* __restrict__ w2r, const void* __restrict__ b2,
    const void* __restrict__ wl,  const void* __restrict__ bl,
    float* __restrict__ wbuf, unsigned short* __restrict__ Wt,
    int* __restrict__ flags, const void* __restrict__ x_in,
    unsigned short* __restrict__ x16, int n8) {
    __shared__ int cnt_bf, cnt_nz;
    int tid = threadIdx.x;
    if (tid == 0) { cnt_bf = 0; cnt_nz = 0; }
    __syncthreads();
    unsigned short h = xh[tid * 2];
    int e = (h >> 7) & 0xFF;
    if (e >= 110 && e <= 132) atomicAdd(&cnt_bf, 1);
    if (ei32[tid * 2 + 1] != 0) atomicAdd(&cnt_nz, 1);
    __syncthreads();
    int f0 = (cnt_bf >= 128) ? 1 : 0;
    if (blockIdx.x == 0 && tid == 0) {
        flags[0] = f0;
        flags[1] = (cnt_nz < 8) ? 1 : 0;
    }
    int i = blockIdx.x * 256 + tid;
    // weights (blocks 0..65): wbuf f32 + Wt bf16-transposed
    if (i < 16642) {
        const void* src; int off;
        if      (i < 4096)  { src = w1a; off = i; }
        else if (i < 8192)  { src = w1r; off = i - 4096; }
        else if (i < 8256)  { src = b1;  off = i - 8192; }
        else if (i < 12352) { src = w2a; off = i - 8256; }
        else if (i < 16448) { src = w2r; off = i - 12352; }
        else if (i < 16512) { src = b2;  off = i - 16448; }
        else if (i < 16640) { src = wl;  off = i - 16512; }
        else                { src = bl;  off = i - 16640; }
        float v = f0 ? bflo2f(((const unsigned short*)src)[off])
                     : ((const float*)src)[off];
        wbuf[i] = v;
        unsigned short hv = f2bf(v);   // exact round-trip when input was bf16
        if (i < 4096)                      Wt[(off & 63) * 128 + (off >> 6)] = hv;
        else if (i < 8192)                 Wt[(off & 63) * 128 + 64 + (off >> 6)] = hv;
        else if (i >= 8256 && i < 12352)   Wt[8192 + (off & 63) * 128 + (off >> 6)] = hv;
        else if (i >= 12352 && i < 16448)  Wt[8192 + (off & 63) * 128 + 64 + (off >> 6)] = hv;
    }
    // x -> bf16 (fp32 path only)
    if (!f0 && i < n8) {
        float4 a = ((const float4*)x_in)[2 * i];
        float4 b = ((const float4*)x_in)[2 * i + 1];
        uint4 o;
        o.x = (unsigned int)f2bf(a.x) | ((unsigned int)f2bf(a.y) << 16);
        o.y = (unsigned int)f2bf(a.z) | ((unsigned int)f2bf(a.w) << 16);
        o.z = (unsigned int)f2bf(b.x) | ((unsigned int)f2bf(b.y) << 16);
        o.w = (unsigned int)f2bf(b.z) | ((unsigned int)f2bf(b.w) << 16);
        ((uint4*)x16)[i] = o;
    }
}

// ---------- P1: per-chunk bucket histogram (bucket = dst >> 8; dst-only read) ----------
__global__ __launch_bounds__(256) void p1_hist_kernel(
    const int* __restrict__ ei32, int* __restrict__ hist,
    int E, int N, int NB, int EC, const int* __restrict__ flags) {
    __shared__ int lh[MAX_NB];
    int tid = threadIdx.x, c = blockIdx.x;
    for (int i = tid; i < NB; i += 256) lh[i] = 0;
    __syncthreads();
    int idx64 = flags[1];
    long base = (long)c * CHUNK;
#pragma unroll 4
    for (int j = 0; j < CHUNK / 256; ++j) {
        long e = base + j * 256 + tid;
        if (e < E) {
            int d = idx64 ? ei32[2 * ((long)E + e)] : ei32[(long)E + e];
            if ((unsigned)d < (unsigned)N)
                atomicAdd(&lh[d >> 8], 1);
        }
    }
    __syncthreads();
    for (int k = tid; k < NB; k += 256) hist[(long)k * EC + c] = lh[k];
}

// ---------- scan: multi-block scan1 + scan3 ----------
__global__ __launch_bounds__(256) void scan1_kernel(const int* __restrict__ in,
                                                    int* __restrict__ out,
                                                    int* __restrict__ blocksum, int n) {
    int tid = threadIdx.x;
    int base = blockIdx.x * 2048 + tid * 8;
    int v[8];
    int tsum = 0;
#pragma unroll
    for (int i = 0; i < 8; ++i) {
        v[i] = (base + i < n) ? in[base + i] : 0;
        tsum += v[i];
    }
    int lane = tid & 63;
    int x = tsum;
#pragma unroll
    for (int off = 1; off < 64; off <<= 1) {
        int y = __shfl_up(x, off);
        if (lane >= off) x += y;
    }
    __shared__ int wsum[4];
    int wave = tid >> 6;
    if (lane == 63) wsum[wave] = x;
    __syncthreads();
    int woff = 0;
#pragma unroll
    for (int w = 0; w < 4; ++w) if (w < wave) woff += wsum[w];
    int run = woff + x - tsum;
#pragma unroll
    for (int i = 0; i < 8; ++i) {
        if (base + i < n) out[base + i] = run;
        run += v[i];
    }
    if (tid == 255) blocksum[blockIdx.x] = woff + x;
}

__global__ void scan3_kernel(int* __restrict__ out, const int* __restrict__ blocksum, int n) {
    int i = blockIdx.x * 256 + threadIdx.x;
    if (i >= n) return;
    int nb = i >> 11;
    int pre = 0;
    for (int b = 0; b < nb; ++b) pre += blocksum[b];
    out[i] += pre;
}

// ---------- P3: scatter packed edges into bucket-major order ----------
// packed = src | ((dst & 255) << 20)   (requires N < 2^20)
__global__ __launch_bounds__(256) void p3_scatter_kernel(
    const int* __restrict__ ei32, const int* __restrict__ hscan,
    int* __restrict__ bkt, int E, int N, int NB, int EC,
    const int* __restrict__ flags) {
    __shared__ int lh[MAX_NB];
    int tid = threadIdx.x, c = blockIdx.x;
    for (int i = tid; i < NB; i += 256) lh[i] = 0;
    __syncthreads();
    int idx64 = flags[1];
    long base = (long)c * CHUNK;
#pragma unroll 4
    for (int j = 0; j < CHUNK / 256; ++j) {
        long e = base + j * 256 + tid;
        if (e < E) {
            int s = idx64 ? ei32[2 * e]             : ei32[e];
            int d = idx64 ? ei32[2 * ((long)E + e)] : ei32[(long)E + e];
            if ((unsigned)d < (unsigned)N) {
                if ((unsigned)s >= (unsigned)N) s = 0;   // clamp (memory safety)
                int k = d >> 8;
                int r = atomicAdd(&lh[k], 1);
                bkt[hscan[(long)k * EC + c] + r] = s | ((d & 255) << 20);
            }
        }
    }
}

// ---------- P4: per-bucket CSR finalize ----------
__global__ __launch_bounds__(256) void p4_build_kernel(
    const int* __restrict__ bkt, const int* __restrict__ hscan, const int* __restrict__ hist,
    int* __restrict__ offs, int* __restrict__ cnt, int* __restrict__ srcs,
    int E, int N, int NB, int EC) {
    int k = blockIdx.x, tid = threadIdx.x;
    int start = hscan[(long)k * EC];
    int end = (k + 1 < NB) ? hscan[(long)(k + 1) * EC]
                           : (hscan[(long)NB * EC - 1] + hist[(long)NB * EC - 1]);
    __shared__ int lc[256], lheads[256], wsum[4];
    lc[tid] = 0;
    __syncthreads();
    for (int e = start + tid; e < end; e += 256)
        atomicAdd(&lc[(bkt[e] >> 20) & 255], 1);
    __syncthreads();
    int cv = lc[tid];
    int lane = tid & 63, wave = tid >> 6;
    int x = cv;
#pragma unroll
    for (int off = 1; off < 64; off <<= 1) {
        int y = __shfl_up(x, off);
        if (lane >= off) x += y;
    }
    if (lane == 63) wsum[wave] = x;
    __syncthreads();
    int woff = 0;
#pragma unroll
    for (int w = 0; w < 4; ++w) if (w < wave) woff += wsum[w];
    int excl = woff + x - cv;
    int gnode = k * 256 + tid;
    if (gnode < N) { offs[gnode] = start + excl; cnt[gnode] = cv; }
    lheads[tid] = excl;
    __syncthreads();
    for (int e = start + tid; e < end; e += 256) {
        int p = bkt[e];
        int d8 = (p >> 20) & 255;
        int pos = start + atomicAdd(&lheads[d8], 1);
        srcs[pos] = p & 0xFFFFF;
    }
}

// ---------- 5. gather-aggregate: 8 nodes per wave, lane group owns one node ----------
// lane = g*8 + li: group g handles node (wave_node_base + g), lane covers feats
// 8*li..8*li+7 (uint4). Serial over the node's edges, unroll 8 -> 8 gathers in
// flight (L3-latency hiding); NO cross-lane reduction; 1 KB coalesced store/wave.
__global__ __launch_bounds__(256) void aggregate_kernel(
    const void* __restrict__ feat_raw, const unsigned short* __restrict__ feat_ws,
    const int* __restrict__ srcs,
    const int* __restrict__ offs, const int* __restrict__ cnt,
    unsigned short* __restrict__ agg16, int N, const int* __restrict__ flags) {
    const unsigned short* feat16 = flags[0] ? (const unsigned short*)feat_raw : feat_ws;
    int tid = threadIdx.x;
    int lane = tid & 63;
    int wave = tid >> 6;
    int g = lane >> 3;
    int li = lane & 7;
    int node = (blockIdx.x * 4 + wave) * 8 + g;
    if (node >= N) return;
    int start = offs[node];
    int deg = cnt[node];
    f32x2 a0 = {0.f, 0.f}, a1 = a0, a2 = a0, a3 = a0;
    int j = 0;
    for (; j + 8 <= deg; j += 8) {
        int s0 = srcs[start + j];
        int s1 = srcs[start + j + 1];
        int s2 = srcs[start + j + 2];
        int s3 = srcs[start + j + 3];
        int s4 = srcs[start + j + 4];
        int s5 = srcs[start + j + 5];
        int s6 = srcs[start + j + 6];
        int s7 = srcs[start + j + 7];
        uint4 u0 = *(const uint4*)(feat16 + (size_t)s0 * FEAT + 8 * li);
        uint4 u1 = *(const uint4*)(feat16 + (size_t)s1 * FEAT + 8 * li);
        uint4 u2 = *(const uint4*)(feat16 + (size_t)s2 * FEAT + 8 * li);
        uint4 u3 = *(const uint4*)(feat16 + (size_t)s3 * FEAT + 8 * li);
        uint4 u4 = *(const uint4*)(feat16 + (size_t)s4 * FEAT + 8 * li);
        uint4 u5 = *(const uint4*)(feat16 + (size_t)s5 * FEAT + 8 * li);
        uint4 u6 = *(const uint4*)(feat16 + (size_t)s6 * FEAT + 8 * li);
        uint4 u7 = *(const uint4*)(feat16 + (size_t)s7 * FEAT + 8 * li);
        a0 += bfpair(u0.x); a1 += bfpair(u0.y); a2 += bfpair(u0.z); a3 += bfpair(u0.w);
        a0 += bfpair(u1.x); a1 += bfpair(u1.y); a2 += bfpair(u1.z); a3 += bfpair(u1.w);
        a0 += bfpair(u2.x); a1 += bfpair(u2.y); a2 += bfpair(u2.z); a3 += bfpair(u2.w);
        a0 += bfpair(u3.x); a1 += bfpair(u3.y); a2 += bfpair(u3.z); a3 += bfpair(u3.w);
        a0 += bfpair(u4.x); a1 += bfpair(u4.y); a2 += bfpair(u4.z); a3 += bfpair(u4.w);
        a0 += bfpair(u5.x); a1 += bfpair(u5.y); a2 += bfpair(u5.z); a3 += bfpair(u5.w);
        a0 += bfpair(u6.x); a1 += bfpair(u6.y); a2 += bfpair(u6.z); a3 += bfpair(u6.w);
        a0 += bfpair(u7.x); a1 += bfpair(u7.y); a2 += bfpair(u7.z); a3 += bfpair(u7.w);
    }
    for (; j < deg; ++j) {
        int s = srcs[start + j];
        uint4 u = *(const uint4*)(feat16 + (size_t)s * FEAT + 8 * li);
        a0 += bfpair(u.x); a1 += bfpair(u.y); a2 += bfpair(u.z); a3 += bfpair(u.w);
    }
    float inv = 1.0f / (float)(deg > 0 ? deg : 1);
    uint4 o;
    o.x = (unsigned)f2bf(a0.x * inv) | ((unsigned)f2bf(a0.y * inv) << 16);
    o.y = (unsigned)f2bf(a1.x * inv) | ((unsigned)f2bf(a1.y * inv) << 16);
    o.z = (unsigned)f2bf(a2.x * inv) | ((unsigned)f2bf(a2.y * inv) << 16);
    o.w = (unsigned)f2bf(a3.x * inv) | ((unsigned)f2bf(a3.y * inv) << 16);
    *(uint4*)(agg16 + (size_t)node * FEAT + 8 * li) = o;
}

// ---------- 6. MFMA SAGE GEMM: out16 = bf16(relu([agg16|root16] @ Wt^T + b)) ----------
// 256 thr = 4 waves; wave w -> rows 16w..16w+15, cols 0..63; 16x16x32 bf16 MFMA
// out16 nullable (layer 2: output fully consumed by fused projection)
__global__ __launch_bounds__(256) void sage_gemm_kernel(
    const unsigned short* __restrict__ agg16,
    const void* __restrict__ root_raw, const unsigned short* __restrict__ root_ws,
    const unsigned short* __restrict__ Wt, const float* __restrict__ bias,
    unsigned short* __restrict__ out16, int N,
    const float* __restrict__ wl, const float* __restrict__ bl,
    void* __restrict__ out_final, const int* __restrict__ flags, int root_sel) {

    const unsigned short* root16 =
        (root_sel && !flags[0]) ? root_ws : (const unsigned short*)root_raw;

    __shared__ unsigned short A_l[64][136];   // stride 68 dwords -> 2-way (free)
    __shared__ unsigned short B_l[64][136];   // Wt[n][k]

    int tid = threadIdx.x;
    int blk = blockIdx.x;

    // stage B: 1024 chunks of 8 shorts (B is 64 rows x 128 k)
#pragma unroll
    for (int i = 0; i < 4; ++i) {
        int ch = tid + i * 256;
        int n = ch >> 4, kc = ch & 15;
        *(uint4*)&B_l[n][kc * 8] = *(const uint4*)(Wt + n * 128 + kc * 8);
    }
    // stage A: rows = [agg16 | root16] (64 rows x 128 k)
#pragma unroll
    for (int i = 0; i < 4; ++i) {
        int ch = tid + i * 256;
        int r = ch >> 4, c = ch & 15;
        int row = blk * 64 + r;
        uint4 u = make_uint4(0, 0, 0, 0);
        if (row < N)
            u = (c < 8) ? ((const uint4*)(agg16 + (size_t)row * FEAT))[c]
                        : ((const uint4*)(root16 + (size_t)row * FEAT))[c - 8];
        *(uint4*)&A_l[r][c * 8] = u;
    }
    __syncthreads();

    int lane = tid & 63;
    int wave = tid >> 6;
    int r0 = wave * 16;
    int m = lane & 15, quad = lane >> 4;

    f32x4 acc0 = {0.f, 0.f, 0.f, 0.f};
    f32x4 acc1 = acc0, acc2 = acc0, acc3 = acc0;

#pragma unroll
    for (int k0 = 0; k0 < 128; k0 += 32) {
        bf16x8 a = *(const bf16x8*)&A_l[r0 + m][k0 + quad * 8];
        bf16x8 b0 = *(const bf16x8*)&B_l[ 0 + m][k0 + quad * 8];
        bf16x8 b1 = *(const bf16x8*)&B_l[16 + m][k0 + quad * 8];
        bf16x8 b2 = *(const bf16x8*)&B_l[32 + m][k0 + quad * 8];
        bf16x8 b3 = *(const bf16x8*)&B_l[48 + m][k0 + quad * 8];
        acc0 = __builtin_amdgcn_mfma_f32_16x16x32_bf16(a, b0, acc0, 0, 0, 0);
        acc1 = __builtin_amdgcn_mfma_f32_16x16x32_bf16(a, b1, acc1, 0, 0, 0);
        acc2 = __builtin_amdgcn_mfma_f32_16x16x32_bf16(a, b2, acc2, 0, 0, 0);
        acc3 = __builtin_amdgcn_mfma_f32_16x16x32_bf16(a, b3, acc3, 0, 0, 0);
    }
    __syncthreads();   // done reading A_l; reuse as C staging

    // epilogue: +bias, relu, bf16 -> A_l[row][col]  (C/D: col=lane&15, row=quad*4+reg)
#pragma unroll
    for (int c = 0; c < 4; ++c) {
        f32x4 av = (c == 0) ? acc0 : (c == 1) ? acc1 : (c == 2) ? acc2 : acc3;
        float bv = bias[c * 16 + m];
#pragma unroll
        for (int reg = 0; reg < 4; ++reg) {
            float v = fmaxf(av[reg] + bv, 0.f);
            A_l[r0 + quad * 4 + reg][c * 16 + m] = f2bf(v);
        }
    }
    __syncthreads();

    // coalesced store of C rows (layer 1 only): 512 uint4 chunks
    if (out16) {
#pragma unroll
        for (int i = 0; i < 2; ++i) {
            int ch = tid + i * 256;
            int r = ch >> 3, c = ch & 7;
            int row = blk * 64 + r;
            if (row < N)
                ((uint4*)(out16 + (size_t)row * FEAT))[c] = *(const uint4*)&A_l[r][c * 8];
        }
    }

    // fused final projection (layer 2): 4 threads per row, 16 feats each
    if (wl) {
        int r = tid >> 2, part = tid & 3;
        int row = blk * 64 + r;
        if (row < N) {
            float p0 = 0.f, p1 = 0.f;
#pragma unroll
            for (int j = 0; j < 16; ++j) {
                int f = part * 16 + j;
                float v = bflo2f(A_l[r][f]);
                p0 += v * wl[f * 2 + 0];
                p1 += v * wl[f * 2 + 1];
            }
            p0 += __shfl_down(p0, 2, 4); p0 += __shfl_down(p0, 1, 4);
            p1 += __shfl_down(p1, 2, 4); p1 += __shfl_down(p1, 1, 4);
            if (part == 0) {
                p0 += bl[0];
                p1 += bl[1];
                if (flags[0]) {
                    unsigned int o = ((unsigned int)f2bf(p1) << 16) | (unsigned int)f2bf(p0);
                    ((unsigned int*)out_final)[row] = o;
                } else {
                    ((float2*)out_final)[row] = make_float2(p0, p1);
                }
            }
        }
    }
}

extern "C" void kernel_launch(void* const* d_in, const int* in_sizes, int n_in,
                              void* d_out, int out_size, void* d_ws, size_t ws_size,
                              hipStream_t stream) {
    const void* x_in = d_in[0];
    const int*  ei32 = (const int*)d_in[1];

    int N = in_sizes[0] / FEAT;
    int E = in_sizes[1] / 2;
    int NB = (N + 255) >> 8;
    int EC = (E + CHUNK - 1) / CHUNK;
    int HN = NB * EC;

    // workspace layout
    unsigned short* x16   = (unsigned short*)d_ws;                 // N*64 bf16 (fp32-input path)
    unsigned short* h16   = x16 + (size_t)N * FEAT;                // N*64
    unsigned short* agg16 = h16 + (size_t)N * FEAT;                // N*64
    unsigned short* Wt    = agg16 + (size_t)N * FEAT;              // 16384
    float*          wbuf  = (float*)(Wt + 16384);                  // 16704
    int*            hist  = (int*)(wbuf + 16704);                  // HN
    int*            hscan = hist + HN;                             // HN
    int*            bsum  = hscan + HN;                            // <=1024
    int*            flags = bsum + 1024;                           // 16
    int*            offs  = flags + 16;                            // N
    int*            cnt   = offs + N;                              // N
    int*            bkt   = cnt + N;                               // E
    int*            srcs  = bkt + E;                               // E

    float* b1_32 = wbuf + 8192;
    float* b2_32 = wbuf + 16448;
    float* wl32  = wbuf + 16512;
    float* bl32  = wbuf + 16640;

    // 0. prep: detect (per-block local) + weights + x conversion, one launch
    int n8 = N * FEAT / 8;
    int pBlocks = (n8 + 255) / 256;
    if (pBlocks < 66) pBlocks = 66;
    prep_kernel<<<pBlocks, 256, 0, stream>>>(
        (const unsigned short*)x_in, ei32,
        d_in[2], d_in[3], d_in[4], d_in[5], d_in[6], d_in[7], d_in[8], d_in[9],
        wbuf, Wt, flags, x_in, x16, n8);

    // 1. CSR build: hist -> scan (parallel) -> scatter -> finalize
    p1_hist_kernel<<<EC, 256, 0, stream>>>(ei32, hist, E, N, NB, EC, flags);
    int sB = (HN + 2047) / 2048;
    scan1_kernel<<<sB, 256, 0, stream>>>(hist, hscan, bsum, HN);
    scan3_kernel<<<(HN + 255) / 256, 256, 0, stream>>>(hscan, bsum, HN);
    p3_scatter_kernel<<<EC, 256, 0, stream>>>(ei32, hscan, bkt, E, N, NB, EC, flags);
    p4_build_kernel<<<NB, 256, 0, stream>>>(bkt, hscan, hist, offs, cnt, srcs, E, N, NB, EC);

    int aBlocks = (N + 31) / 32;   // 8 nodes per wave, 4 waves per block
    int gBlocks = (N + 63) / 64;

    // 2. layer 1 (x read directly from input when bf16)
    aggregate_kernel<<<aBlocks, 256, 0, stream>>>(x_in, x16, srcs, offs, cnt, agg16, N, flags);
    sage_gemm_kernel<<<gBlocks, 256, 0, stream>>>(agg16, x_in, x16, Wt, b1_32, h16, N,
                                                  nullptr, nullptr, nullptr, flags, 1);

    // 3. layer 2 + fused final projection (h2 never leaves LDS; no h16 write)
    aggregate_kernel<<<aBlocks, 256, 0, stream>>>(h16, h16, srcs, offs, cnt, agg16, N, flags);
    sage_gemm_kernel<<<gBlocks, 256, 0, stream>>>(agg16, h16, h16, Wt + 8192, b2_32, nullptr, N,
                                                  wl32, bl32, d_out, flags, 0);
}

// Round 16
// 229.912 us; speedup vs baseline: 1.0438x; 1.0438x over previous
//
#include <hip/hip_runtime.h>
#include <hip/hip_bf16.h>

#define FEAT 64
#define CHUNK 8192   // edges per P1/P3 block
#define MAX_NB 1024  // max buckets (N <= 262144)

typedef __attribute__((ext_vector_type(8))) short bf16x8;
typedef __attribute__((ext_vector_type(4))) float f32x4;
typedef __attribute__((ext_vector_type(2))) float f32x2;

// ---------- bf16 helpers ----------
__device__ __forceinline__ float bflo2f(unsigned int u) {
    union { unsigned int u; float f; } v; v.u = u << 16; return v.f;
}
__device__ __forceinline__ float bfhi2f(unsigned int u) {
    union { unsigned int u; float f; } v; v.u = u & 0xffff0000u; return v.f;
}
__device__ __forceinline__ unsigned short f2bf(float f) {
    union { float f; unsigned int u; } v; v.f = f;
    unsigned int u = v.u;
    u += 0x7fffu + ((u >> 16) & 1u);   // round-to-nearest-even
    return (unsigned short)(u >> 16);
}
__device__ __forceinline__ f32x2 bfpair(unsigned int u) {
    f32x2 r; r.x = bflo2f(u & 0xffffu); r.y = bfhi2f(u); return r;
}

// ---------- 0. prep: per-block dtype detect + weight conversion + x conversion ----------
__global__ __launch_bounds__(256) void prep_kernel(
    const unsigned short* __restrict__ xh, const int* __restrict__ ei32,
    const void* __restrict__ w1a, const void* __restrict__ w1r,
    const void* __restrict__ b1,  const void* __restrict__ w2a,
    const void* __restrict__ w2r, const void* __restrict__ b2,
    const void* __restrict__ wl,  const void* __restrict__ bl,
    float* __restrict__ wbuf, unsigned short* __restrict__ Wt,
    int* __restrict__ flags, const void* __restrict__ x_in,
    unsigned short* __restrict__ x16, int n8) {
    __shared__ int cnt_bf, cnt_nz;
    int tid = threadIdx.x;
    if (tid == 0) { cnt_bf = 0; cnt_nz = 0; }
    __syncthreads();
    unsigned short h = xh[tid * 2];
    int e = (h >> 7) & 0xFF;
    if (e >= 110 && e <= 132) atomicAdd(&cnt_bf, 1);
    if (ei32[tid * 2 + 1] != 0) atomicAdd(&cnt_nz, 1);
    __syncthreads();
    int f0 = (cnt_bf >= 128) ? 1 : 0;
    if (blockIdx.x == 0 && tid == 0) {
        flags[0] = f0;
        flags[1] = (cnt_nz < 8) ? 1 : 0;
    }
    int i = blockIdx.x * 256 + tid;
    // weights (blocks 0..65): wbuf f32 + Wt bf16-transposed
    if (i < 16642) {
        const void* src; int off;
        if      (i < 4096)  { src = w1a; off = i; }
        else if (i < 8192)  { src = w1r; off = i - 4096; }
        else if (i < 8256)  { src = b1;  off = i - 8192; }
        else if (i < 12352) { src = w2a; off = i - 8256; }
        else if (i < 16448) { src = w2r; off = i - 12352; }
        else if (i < 16512) { src = b2;  off = i - 16448; }
        else if (i < 16640) { src = wl;  off = i - 16512; }
        else                { src = bl;  off = i - 16640; }
        float v = f0 ? bflo2f(((const unsigned short*)src)[off])
                     : ((const float*)src)[off];
        wbuf[i] = v;
        unsigned short hv = f2bf(v);   // exact round-trip when input was bf16
        if (i < 4096)                      Wt[(off & 63) * 128 + (off >> 6)] = hv;
        else if (i < 8192)                 Wt[(off & 63) * 128 + 64 + (off >> 6)] = hv;
        else if (i >= 8256 && i < 12352)   Wt[8192 + (off & 63) * 128 + (off >> 6)] = hv;
        else if (i >= 12352 && i < 16448)  Wt[8192 + (off & 63) * 128 + 64 + (off >> 6)] = hv;
    }
    // x -> bf16 (fp32 path only)
    if (!f0 && i < n8) {
        float4 a = ((const float4*)x_in)[2 * i];
        float4 b = ((const float4*)x_in)[2 * i + 1];
        uint4 o;
        o.x = (unsigned int)f2bf(a.x) | ((unsigned int)f2bf(a.y) << 16);
        o.y = (unsigned int)f2bf(a.z) | ((unsigned int)f2bf(a.w) << 16);
        o.z = (unsigned int)f2bf(b.x) | ((unsigned int)f2bf(b.y) << 16);
        o.w = (unsigned int)f2bf(b.z) | ((unsigned int)f2bf(b.w) << 16);
        ((uint4*)x16)[i] = o;
    }
}

// ---------- P1: per-chunk bucket histogram (bucket = dst >> 8; dst-only read) ----------
__global__ __launch_bounds__(256) void p1_hist_kernel(
    const int* __restrict__ ei32, int* __restrict__ hist,
    int E, int N, int NB, int EC, const int* __restrict__ flags) {
    __shared__ int lh[MAX_NB];
    int tid = threadIdx.x, c = blockIdx.x;
    for (int i = tid; i < NB; i += 256) lh[i] = 0;
    __syncthreads();
    int idx64 = flags[1];
    long base = (long)c * CHUNK;
#pragma unroll 4
    for (int j = 0; j < CHUNK / 256; ++j) {
        long e = base + j * 256 + tid;
        if (e < E) {
            int d = idx64 ? ei32[2 * ((long)E + e)] : ei32[(long)E + e];
            if ((unsigned)d < (unsigned)N)
                atomicAdd(&lh[d >> 8], 1);
        }
    }
    __syncthreads();
    for (int k = tid; k < NB; k += 256) hist[(long)k * EC + c] = lh[k];
}

// ---------- scan: multi-block scan1 + scan3 ----------
__global__ __launch_bounds__(256) void scan1_kernel(const int* __restrict__ in,
                                                    int* __restrict__ out,
                                                    int* __restrict__ blocksum, int n) {
    int tid = threadIdx.x;
    int base = blockIdx.x * 2048 + tid * 8;
    int v[8];
    int tsum = 0;
#pragma unroll
    for (int i = 0; i < 8; ++i) {
        v[i] = (base + i < n) ? in[base + i] : 0;
        tsum += v[i];
    }
    int lane = tid & 63;
    int x = tsum;
#pragma unroll
    for (int off = 1; off < 64; off <<= 1) {
        int y = __shfl_up(x, off);
        if (lane >= off) x += y;
    }
    __shared__ int wsum[4];
    int wave = tid >> 6;
    if (lane == 63) wsum[wave] = x;
    __syncthreads();
    int woff = 0;
#pragma unroll
    for (int w = 0; w < 4; ++w) if (w < wave) woff += wsum[w];
    int run = woff + x - tsum;
#pragma unroll
    for (int i = 0; i < 8; ++i) {
        if (base + i < n) out[base + i] = run;
        run += v[i];
    }
    if (tid == 255) blocksum[blockIdx.x] = woff + x;
}

__global__ void scan3_kernel(int* __restrict__ out, const int* __restrict__ blocksum, int n) {
    int i = blockIdx.x * 256 + threadIdx.x;
    if (i >= n) return;
    int nb = i >> 11;
    int pre = 0;
    for (int b = 0; b < nb; ++b) pre += blocksum[b];
    out[i] += pre;
}

// ---------- P3: scatter packed edges into bucket-major order ----------
// packed = src | ((dst & 255) << 20)   (requires N < 2^20)
__global__ __launch_bounds__(256) void p3_scatter_kernel(
    const int* __restrict__ ei32, const int* __restrict__ hscan,
    int* __restrict__ bkt, int E, int N, int NB, int EC,
    const int* __restrict__ flags) {
    __shared__ int lh[MAX_NB];
    int tid = threadIdx.x, c = blockIdx.x;
    for (int i = tid; i < NB; i += 256) lh[i] = 0;
    __syncthreads();
    int idx64 = flags[1];
    long base = (long)c * CHUNK;
#pragma unroll 4
    for (int j = 0; j < CHUNK / 256; ++j) {
        long e = base + j * 256 + tid;
        if (e < E) {
            int s = idx64 ? ei32[2 * e]             : ei32[e];
            int d = idx64 ? ei32[2 * ((long)E + e)] : ei32[(long)E + e];
            if ((unsigned)d < (unsigned)N) {
                if ((unsigned)s >= (unsigned)N) s = 0;   // clamp (memory safety)
                int k = d >> 8;
                int r = atomicAdd(&lh[k], 1);
                bkt[hscan[(long)k * EC + c] + r] = s | ((d & 255) << 20);
            }
        }
    }
}

// ---------- P4: per-bucket CSR finalize ----------
__global__ __launch_bounds__(256) void p4_build_kernel(
    const int* __restrict__ bkt, const int* __restrict__ hscan, const int* __restrict__ hist,
    int* __restrict__ offs, int* __restrict__ cnt, int* __restrict__ srcs,
    int E, int N, int NB, int EC) {
    int k = blockIdx.x, tid = threadIdx.x;
    int start = hscan[(long)k * EC];
    int end = (k + 1 < NB) ? hscan[(long)(k + 1) * EC]
                           : (hscan[(long)NB * EC - 1] + hist[(long)NB * EC - 1]);
    __shared__ int lc[256], lheads[256], wsum[4];
    lc[tid] = 0;
    __syncthreads();
    for (int e = start + tid; e < end; e += 256)
        atomicAdd(&lc[(bkt[e] >> 20) & 255], 1);
    __syncthreads();
    int cv = lc[tid];
    int lane = tid & 63, wave = tid >> 6;
    int x = cv;
#pragma unroll
    for (int off = 1; off < 64; off <<= 1) {
        int y = __shfl_up(x, off);
        if (lane >= off) x += y;
    }
    if (lane == 63) wsum[wave] = x;
    __syncthreads();
    int woff = 0;
#pragma unroll
    for (int w = 0; w < 4; ++w) if (w < wave) woff += wsum[w];
    int excl = woff + x - cv;
    int gnode = k * 256 + tid;
    if (gnode < N) { offs[gnode] = start + excl; cnt[gnode] = cv; }
    lheads[tid] = excl;
    __syncthreads();
    for (int e = start + tid; e < end; e += 256) {
        int p = bkt[e];
        int d8 = (p >> 20) & 255;
        int pos = start + atomicAdd(&lheads[d8], 1);
        srcs[pos] = p & 0xFFFFF;
    }
}

// ---------- 5. gather-aggregate: 8 nodes per wave, lane group owns one node ----------
// lane = g*8 + li: group g handles node (wave_node_base + g), lane covers feats
// 8*li..8*li+7 (uint4). Serial over the node's edges, unroll 4 (measured best:
// unroll-8 regressed — tail serial-latency cost exceeds pipelining gain at
// avg deg 16); NO cross-lane reduction; 1 KB coalesced store per wave.
__global__ __launch_bounds__(256) void aggregate_kernel(
    const void* __restrict__ feat_raw, const unsigned short* __restrict__ feat_ws,
    const int* __restrict__ srcs,
    const int* __restrict__ offs, const int* __restrict__ cnt,
    unsigned short* __restrict__ agg16, int N, const int* __restrict__ flags) {
    const unsigned short* feat16 = flags[0] ? (const unsigned short*)feat_raw : feat_ws;
    int tid = threadIdx.x;
    int lane = tid & 63;
    int wave = tid >> 6;
    int g = lane >> 3;
    int li = lane & 7;
    int node = (blockIdx.x * 4 + wave) * 8 + g;
    if (node >= N) return;
    int start = offs[node];
    int deg = cnt[node];
    f32x2 a0 = {0.f, 0.f}, a1 = a0, a2 = a0, a3 = a0;
    int j = 0;
    for (; j + 4 <= deg; j += 4) {
        int s0 = srcs[start + j];
        int s1 = srcs[start + j + 1];
        int s2 = srcs[start + j + 2];
        int s3 = srcs[start + j + 3];
        uint4 u0 = *(const uint4*)(feat16 + (size_t)s0 * FEAT + 8 * li);
        uint4 u1 = *(const uint4*)(feat16 + (size_t)s1 * FEAT + 8 * li);
        uint4 u2 = *(const uint4*)(feat16 + (size_t)s2 * FEAT + 8 * li);
        uint4 u3 = *(const uint4*)(feat16 + (size_t)s3 * FEAT + 8 * li);
        a0 += bfpair(u0.x); a1 += bfpair(u0.y); a2 += bfpair(u0.z); a3 += bfpair(u0.w);
        a0 += bfpair(u1.x); a1 += bfpair(u1.y); a2 += bfpair(u1.z); a3 += bfpair(u1.w);
        a0 += bfpair(u2.x); a1 += bfpair(u2.y); a2 += bfpair(u2.z); a3 += bfpair(u2.w);
        a0 += bfpair(u3.x); a1 += bfpair(u3.y); a2 += bfpair(u3.z); a3 += bfpair(u3.w);
    }
    for (; j < deg; ++j) {
        int s = srcs[start + j];
        uint4 u = *(const uint4*)(feat16 + (size_t)s * FEAT + 8 * li);
        a0 += bfpair(u.x); a1 += bfpair(u.y); a2 += bfpair(u.z); a3 += bfpair(u.w);
    }
    float inv = 1.0f / (float)(deg > 0 ? deg : 1);
    uint4 o;
    o.x = (unsigned)f2bf(a0.x * inv) | ((unsigned)f2bf(a0.y * inv) << 16);
    o.y = (unsigned)f2bf(a1.x * inv) | ((unsigned)f2bf(a1.y * inv) << 16);
    o.z = (unsigned)f2bf(a2.x * inv) | ((unsigned)f2bf(a2.y * inv) << 16);
    o.w = (unsigned)f2bf(a3.x * inv) | ((unsigned)f2bf(a3.y * inv) << 16);
    *(uint4*)(agg16 + (size_t)node * FEAT + 8 * li) = o;
}

// ---------- 6. MFMA SAGE GEMM: out16 = bf16(relu([agg16|root16] @ Wt^T + b)) ----------
// 256 thr = 4 waves; wave w -> rows 16w..16w+15, cols 0..63; 16x16x32 bf16 MFMA
// out16 nullable (layer 2: output fully consumed by fused projection)
__global__ __launch_bounds__(256) void sage_gemm_kernel(
    const unsigned short* __restrict__ agg16,
    const void* __restrict__ root_raw, const unsigned short* __restrict__ root_ws,
    const unsigned short* __restrict__ Wt, const float* __restrict__ bias,
    unsigned short* __restrict__ out16, int N,
    const float* __restrict__ wl, const float* __restrict__ bl,
    void* __restrict__ out_final, const int* __restrict__ flags, int root_sel) {

    const unsigned short* root16 =
        (root_sel && !flags[0]) ? root_ws : (const unsigned short*)root_raw;

    __shared__ unsigned short A_l[64][136];   // stride 68 dwords -> 2-way (free)
    __shared__ unsigned short B_l[64][136];   // Wt[n][k]

    int tid = threadIdx.x;
    int blk = blockIdx.x;

    // stage B: 1024 chunks of 8 shorts (B is 64 rows x 128 k)
#pragma unroll
    for (int i = 0; i < 4; ++i) {
        int ch = tid + i * 256;
        int n = ch >> 4, kc = ch & 15;
        *(uint4*)&B_l[n][kc * 8] = *(const uint4*)(Wt + n * 128 + kc * 8);
    }
    // stage A: rows = [agg16 | root16] (64 rows x 128 k)
#pragma unroll
    for (int i = 0; i < 4; ++i) {
        int ch = tid + i * 256;
        int r = ch >> 4, c = ch & 15;
        int row = blk * 64 + r;
        uint4 u = make_uint4(0, 0, 0, 0);
        if (row < N)
            u = (c < 8) ? ((const uint4*)(agg16 + (size_t)row * FEAT))[c]
                        : ((const uint4*)(root16 + (size_t)row * FEAT))[c - 8];
        *(uint4*)&A_l[r][c * 8] = u;
    }
    __syncthreads();

    int lane = tid & 63;
    int wave = tid >> 6;
    int r0 = wave * 16;
    int m = lane & 15, quad = lane >> 4;

    f32x4 acc0 = {0.f, 0.f, 0.f, 0.f};
    f32x4 acc1 = acc0, acc2 = acc0, acc3 = acc0;

#pragma unroll
    for (int k0 = 0; k0 < 128; k0 += 32) {
        bf16x8 a = *(const bf16x8*)&A_l[r0 + m][k0 + quad * 8];
        bf16x8 b0 = *(const bf16x8*)&B_l[ 0 + m][k0 + quad * 8];
        bf16x8 b1 = *(const bf16x8*)&B_l[16 + m][k0 + quad * 8];
        bf16x8 b2 = *(const bf16x8*)&B_l[32 + m][k0 + quad * 8];
        bf16x8 b3 = *(const bf16x8*)&B_l[48 + m][k0 + quad * 8];
        acc0 = __builtin_amdgcn_mfma_f32_16x16x32_bf16(a, b0, acc0, 0, 0, 0);
        acc1 = __builtin_amdgcn_mfma_f32_16x16x32_bf16(a, b1, acc1, 0, 0, 0);
        acc2 = __builtin_amdgcn_mfma_f32_16x16x32_bf16(a, b2, acc2, 0, 0, 0);
        acc3 = __builtin_amdgcn_mfma_f32_16x16x32_bf16(a, b3, acc3, 0, 0, 0);
    }
    __syncthreads();   // done reading A_l; reuse as C staging

    // epilogue: +bias, relu, bf16 -> A_l[row][col]  (C/D: col=lane&15, row=quad*4+reg)
#pragma unroll
    for (int c = 0; c < 4; ++c) {
        f32x4 av = (c == 0) ? acc0 : (c == 1) ? acc1 : (c == 2) ? acc2 : acc3;
        float bv = bias[c * 16 + m];
#pragma unroll
        for (int reg = 0; reg < 4; ++reg) {
            float v = fmaxf(av[reg] + bv, 0.f);
            A_l[r0 + quad * 4 + reg][c * 16 + m] = f2bf(v);
        }
    }
    __syncthreads();

    // coalesced store of C rows (layer 1 only): 512 uint4 chunks
    if (out16) {
#pragma unroll
        for (int i = 0; i < 2; ++i) {
            int ch = tid + i * 256;
            int r = ch >> 3, c = ch & 7;
            int row = blk * 64 + r;
            if (row < N)
                ((uint4*)(out16 + (size_t)row * FEAT))[c] = *(const uint4*)&A_l[r][c * 8];
        }
    }

    // fused final projection (layer 2): 4 threads per row, 16 feats each
    if (wl) {
        int r = tid >> 2, part = tid & 3;
        int row = blk * 64 + r;
        if (row < N) {
            float p0 = 0.f, p1 = 0.f;
#pragma unroll
            for (int j = 0; j < 16; ++j) {
                int f = part * 16 + j;
                float v = bflo2f(A_l[r][f]);
                p0 += v * wl[f * 2 + 0];
                p1 += v * wl[f * 2 + 1];
            }
            p0 += __shfl_down(p0, 2, 4); p0 += __shfl_down(p0, 1, 4);
            p1 += __shfl_down(p1, 2, 4); p1 += __shfl_down(p1, 1, 4);
            if (part == 0) {
                p0 += bl[0];
                p1 += bl[1];
                if (flags[0]) {
                    unsigned int o = ((unsigned int)f2bf(p1) << 16) | (unsigned int)f2bf(p0);
                    ((unsigned int*)out_final)[row] = o;
                } else {
                    ((float2*)out_final)[row] = make_float2(p0, p1);
                }
            }
        }
    }
}

extern "C" void kernel_launch(void* const* d_in, const int* in_sizes, int n_in,
                              void* d_out, int out_size, void* d_ws, size_t ws_size,
                              hipStream_t stream) {
    const void* x_in = d_in[0];
    const int*  ei32 = (const int*)d_in[1];

    int N = in_sizes[0] / FEAT;
    int E = in_sizes[1] / 2;
    int NB = (N + 255) >> 8;
    int EC = (E + CHUNK - 1) / CHUNK;
    int HN = NB * EC;

    // workspace layout
    unsigned short* x16   = (unsigned short*)d_ws;                 // N*64 bf16 (fp32-input path)
    unsigned short* h16   = x16 + (size_t)N * FEAT;                // N*64
    unsigned short* agg16 = h16 + (size_t)N * FEAT;                // N*64
    unsigned short* Wt    = agg16 + (size_t)N * FEAT;              // 16384
    float*          wbuf  = (float*)(Wt + 16384);                  // 16704
    int*            hist  = (int*)(wbuf + 16704);                  // HN
    int*            hscan = hist + HN;                             // HN
    int*            bsum  = hscan + HN;                            // <=1024
    int*            flags = bsum + 1024;                           // 16
    int*            offs  = flags + 16;                            // N
    int*            cnt   = offs + N;                              // N
    int*            bkt   = cnt + N;                               // E
    int*            srcs  = bkt + E;                               // E

    float* b1_32 = wbuf + 8192;
    float* b2_32 = wbuf + 16448;
    float* wl32  = wbuf + 16512;
    float* bl32  = wbuf + 16640;

    // 0. prep: detect (per-block local) + weights + x conversion, one launch
    int n8 = N * FEAT / 8;
    int pBlocks = (n8 + 255) / 256;
    if (pBlocks < 66) pBlocks = 66;
    prep_kernel<<<pBlocks, 256, 0, stream>>>(
        (const unsigned short*)x_in, ei32,
        d_in[2], d_in[3], d_in[4], d_in[5], d_in[6], d_in[7], d_in[8], d_in[9],
        wbuf, Wt, flags, x_in, x16, n8);

    // 1. CSR build: hist -> scan (parallel) -> scatter -> finalize
    p1_hist_kernel<<<EC, 256, 0, stream>>>(ei32, hist, E, N, NB, EC, flags);
    int sB = (HN + 2047) / 2048;
    scan1_kernel<<<sB, 256, 0, stream>>>(hist, hscan, bsum, HN);
    scan3_kernel<<<(HN + 255) / 256, 256, 0, stream>>>(hscan, bsum, HN);
    p3_scatter_kernel<<<EC, 256, 0, stream>>>(ei32, hscan, bkt, E, N, NB, EC, flags);
    p4_build_kernel<<<NB, 256, 0, stream>>>(bkt, hscan, hist, offs, cnt, srcs, E, N, NB, EC);

    int aBlocks = (N + 31) / 32;   // 8 nodes per wave, 4 waves per block
    int gBlocks = (N + 63) / 64;

    // 2. layer 1 (x read directly from input when bf16)
    aggregate_kernel<<<aBlocks, 256, 0, stream>>>(x_in, x16, srcs, offs, cnt, agg16, N, flags);
    sage_gemm_kernel<<<gBlocks, 256, 0, stream>>>(agg16, x_in, x16, Wt, b1_32, h16, N,
                                                  nullptr, nullptr, nullptr, flags, 1);

    // 3. layer 2 + fused final projection (h2 never leaves LDS; no h16 write)
    aggregate_kernel<<<aBlocks, 256, 0, stream>>>(h16, h16, srcs, offs, cnt, agg16, N, flags);
    sage_gemm_kernel<<<gBlocks, 256, 0, stream>>>(agg16, h16, h16, Wt + 8192, b2_32, nullptr, N,
                                                  wl32, bl32, d_out, flags, 0);
}